// Round 3
// baseline (257.832 us; speedup 1.0000x reference)
//
#include <hip/hip_runtime.h>
#include <hip/hip_bf16.h>
#include <hip/hip_cooperative_groups.h>

namespace cg = cooperative_groups;

// ---------------------------------------------------------------------------
// ContrastiveLoss: B=8192, D=64, fp32 inputs, scalar fp32 output.
// loss = mean_i[ w_i * (-(d_i - lse_row_i) - (d_i - lse_col_i)) ] / 2
//   w_i = (1 - exp(d_i - lse_row_i))^2,  d_i = (img_i . txt_i)/T (fp32 exact)
//   lse_row_i = M + ln( sum_j exp(s_ij - M) ),  M = 1/T  (fixed shift: |s|<=M
//   since both factors are unit vectors -> no max pass needed)
// Trick: imgB rows are pre-scaled by K1 = LOG2E/T and the MFMA C-operand is
// initialized to -K1, so the accumulator exits the matrix pipe as the exp2
// argument directly: acc = K1*dot - K1 = (s - M)*log2(e). Zero VALU fixup.
// This revision: rounds 1-2 proved the kernels' inner work is NOT the cost
// (atomic-free == atomic-heavy == ~84 us, vs ~12 us of modeled kernel work
// next to a 41 us harness poison fill). Remaining slack = dispatch-boundary
// overhead. Fix: ONE cooperative kernel (1024 blocks co-resident via
// __launch_bounds__(256,4) -> 4 blocks/CU) with two grid.sync()s replacing
// two kernel launches. Phase A: norm (blocks 0..511). Phase B: score (all).
// Phase C: finish spread over all 262144 threads (32 threads/row).
// Fallback to the 3-kernel path if cooperative validation fails.
// ---------------------------------------------------------------------------

#define NB 8192
#define ND 64

constexpr float INV_T = 1.0f / 0.07f;                 // 14.2857...
constexpr float LOG2E = 1.4426950408889634f;
constexpr float LN2   = 0.6931471805599453f;
constexpr float K1    = INV_T * LOG2E;                // exp2 arg scale

typedef float  floatx4 __attribute__((ext_vector_type(4)));
typedef short  bf16x8  __attribute__((ext_vector_type(8)));
typedef short  shortx4 __attribute__((ext_vector_type(4)));

// --------------------------- phase A body: normalize -----------------------
// gw = global wave 0..2047, 4 rows/wave, 16 lanes/row, one float4 per lane.
// Fused 4-step butterfly reduces |x|^2, |t|^2, x.t together. imgB gets the
// K1-prescaled bf16 copy (A side), txtB the plain normalized bf16 (B side).
__device__ __forceinline__
void norm_body(int gw, int lane,
               const float* __restrict__ img, const float* __restrict__ txt,
               __hip_bfloat16* __restrict__ imgB,
               __hip_bfloat16* __restrict__ txtB,
               float* __restrict__ diag)
{
    const int sub = lane >> 4;                               // row within wave
    const int c16 = lane & 15;                               // float4 slot
    const int row = gw * 4 + sub;                            // 0..8191

    const floatx4 x = ((const floatx4*)img)[row * 16 + c16];
    const floatx4 t = ((const floatx4*)txt)[row * 16 + c16];
    float sx  = x[0]*x[0] + x[1]*x[1] + x[2]*x[2] + x[3]*x[3];
    float st  = t[0]*t[0] + t[1]*t[1] + t[2]*t[2] + t[3]*t[3];
    float sxt = x[0]*t[0] + x[1]*t[1] + x[2]*t[2] + x[3]*t[3];
    #pragma unroll
    for (int o = 1; o < 16; o <<= 1) {
        sx  += __shfl_xor(sx,  o, 64);
        st  += __shfl_xor(st,  o, 64);
        sxt += __shfl_xor(sxt, o, 64);
    }
    const float nx = fmaxf(sqrtf(sx), 1e-12f);
    const float nt = fmaxf(sqrtf(st), 1e-12f);
    shortx4 xb, tb;
    #pragma unroll
    for (int j = 0; j < 4; ++j) {
        __hip_bfloat16 hx = __float2bfloat16(x[j] / nx * K1);  // A pre-scaled
        __hip_bfloat16 ht = __float2bfloat16(t[j] / nt);
        xb[j] = *reinterpret_cast<const short*>(&hx);
        tb[j] = *reinterpret_cast<const short*>(&ht);
    }
    ((shortx4*)imgB)[row * 16 + c16] = xb;                    // 8B coalesced
    ((shortx4*)txtB)[row * 16 + c16] = tb;
    if (c16 == 0) diag[row] = sxt / (nx * nt) * INV_T;        // exact fp32 diag
}

// ----------------------- phase B body: streamed score ----------------------
// Block b: chunk = b&31 (256 cols, shared by the 4 waves -> B loads hit L1),
// strip = (b>>5)*4 + wid (64 rows/wave). A-fragments live in registers for
// the whole tile loop; next tile's B software-prefetched (branchless wrap).
// Per 16x16 tile: 2 chained MFMAs (K=64, C init = -K1) x 4 row-tiles, 16
// exp2 straight off the accumulator, row partials in registers, col partial
// via depth-4 tree + 2 shuffles -> LDS slot. Rows exit via a butterfly
// reduce-scatter (15 shuffles) -> plain unique-writer stores.
// mfma_f32_16x16x32_bf16 layouts (HW-verified):
//   A: lane holds A[m=lane&15][k=(lane>>4)*8 + j], j=0..7  (8 contig bf16)
//   B: lane holds B[n=lane&15][k=(lane>>4)*8 + j]          (NT layout)
//   C/D: col = lane&15, row = (lane>>4)*4 + r
__device__ __forceinline__
void score_body(int bid, int wid, int lane, float (*sm)[256],
                const __hip_bfloat16* __restrict__ imgB,
                const __hip_bfloat16* __restrict__ txtB,
                float* __restrict__ rowPart,   // [32][8192]  chunk-major
                float* __restrict__ colPart)   // [32][8192]  strip4-major
{
    const int chunk = bid & 31;               // cols chunk*256..+255
    const int sgrp  = bid >> 5;               // strip group 0..31
    const int strip = sgrp * 4 + wid;         // rows strip*64..+63
    const int m = lane & 15;
    const int q = lane >> 4;

    const bf16x8* __restrict__ A  = (const bf16x8*)imgB;  // units of 8 elems
    const bf16x8* __restrict__ Bp = (const bf16x8*)txtB;

    const int rowbase = strip * 64;
    bf16x8 a[4][2];
    #pragma unroll
    for (int it = 0; it < 4; ++it) {
        const int r = rowbase + it * 16 + m;
        a[it][0] = A[r * 8 + q];        // k = q*8 .. q*8+7
        a[it][1] = A[r * 8 + 4 + q];    // k = 32 + q*8 ..
    }

    const int colbase = chunk * 256 + m;      // this lane's t=0 column
    bf16x8 b0 = Bp[colbase * 8 + q];
    bf16x8 b1 = Bp[colbase * 8 + 4 + q];

    float rs[16];
    #pragma unroll
    for (int i = 0; i < 16; ++i) rs[i] = 0.f;

    const floatx4 NEGK = {-K1, -K1, -K1, -K1};   // bakes the -M shift in

    #pragma unroll 2
    for (int t = 0; t < 16; ++t) {
        // prefetch next tile's B (t=15 wraps to t=0: harmless, avoids branch)
        const int nn = colbase + (((t + 1) & 15) << 4);
        const bf16x8 pb0 = Bp[nn * 8 + q];
        const bf16x8 pb1 = Bp[nn * 8 + 4 + q];

        float csp[4];
        #pragma unroll
        for (int it = 0; it < 4; ++it) {
            floatx4 z   = __builtin_amdgcn_mfma_f32_16x16x32_bf16(a[it][0], b0, NEGK, 0, 0, 0);
            floatx4 acc = __builtin_amdgcn_mfma_f32_16x16x32_bf16(a[it][1], b1, z,    0, 0, 0);
            // acc == (s - M) * log2(e) already
            const float e0 = __builtin_amdgcn_exp2f(acc[0]);
            const float e1 = __builtin_amdgcn_exp2f(acc[1]);
            const float e2 = __builtin_amdgcn_exp2f(acc[2]);
            const float e3 = __builtin_amdgcn_exp2f(acc[3]);
            rs[it * 4 + 0] += e0;
            rs[it * 4 + 1] += e1;
            rs[it * 4 + 2] += e2;
            rs[it * 4 + 3] += e3;
            csp[it] = (e0 + e1) + (e2 + e3);     // depth-2 tree
        }
        float cs = (csp[0] + csp[1]) + (csp[2] + csp[3]);
        // combine the 4 quads -> col sum over this wave's 64 rows
        cs += __shfl_xor(cs, 16, 64);
        cs += __shfl_xor(cs, 32, 64);
        if (q == 0) sm[wid][(t << 4) + m] = cs;   // unique LDS slot, no sync yet
        b0 = pb0; b1 = pb1;
    }

    // Butterfly reduce-scatter over the 16 m-lanes (per q-group):
    // after stage d, lanes whose bit log2(d) of m is set own the upper-half
    // indices. Final: lane m holds the full strip-row sum for idx == m.
#define RS_STAGE(d)                                                     \
    {                                                                   \
        const bool hi = (m & (d)) != 0;                                 \
        _Pragma("unroll")                                               \
        for (int j = 0; j < (d); ++j) {                                 \
            const float va = rs[j], vb = rs[j + (d)];                   \
            const float send = hi ? va : vb;                            \
            const float recv = __shfl_xor(send, (d), 64);               \
            rs[j] = (hi ? vb : va) + recv;                              \
        }                                                               \
    }
    RS_STAGE(8)
    RS_STAGE(4)
    RS_STAGE(2)
    RS_STAGE(1)
#undef RS_STAGE

    // idx == m: it = m>>2, r = m&3; all 64 lanes hit 64 distinct rows.
    // Plain store: (chunk,row) has exactly one writer wave.
    const int row = rowbase + ((m >> 2) << 4) + (q << 2) + (m & 3);
    rowPart[chunk * NB + row] = rs[0];

    // Column combine across the block's 4 waves (strips) -> plain store.
    __syncthreads();
    const int j = threadIdx.x;                 // 0..255
    const float v = (sm[0][j] + sm[1][j]) + (sm[2][j] + sm[3][j]);
    colPart[sgrp * NB + chunk * 256 + j] = v;  // coalesced, unique writer
}

// --------------------------- fused cooperative kernel ----------------------
__global__ __launch_bounds__(256, 4)
void fused_kernel(const float* __restrict__ img, const float* __restrict__ txt,
                  __hip_bfloat16* __restrict__ imgB,
                  __hip_bfloat16* __restrict__ txtB,
                  float* __restrict__ diag,
                  float* __restrict__ rowPart,
                  float* __restrict__ colPart,
                  float* __restrict__ out)
{
    cg::grid_group grid = cg::this_grid();
    const int wid  = threadIdx.x >> 6;
    const int lane = threadIdx.x & 63;

    __shared__ float sm[4][256];

    // ---- phase A: normalize (blocks 0..511; 2048 waves x 4 rows) ----
    if (blockIdx.x == 0 && threadIdx.x == 0) out[0] = 0.f;
    if (blockIdx.x < 512)
        norm_body(blockIdx.x * 4 + wid, lane, img, txt, imgB, txtB, diag);

    grid.sync();

    // ---- phase B: score (all 1024 blocks) ----
    score_body(blockIdx.x, wid, lane, sm, imgB, txtB, rowPart, colPart);

    grid.sync();

    // ---- phase C: finish (32 threads per row index) ----
    {
        const int tg = blockIdx.x * 256 + threadIdx.x;   // 0..262143
        const int i  = tg >> 5;                          // row index 0..8191
        const int p  = threadIdx.x & 31;                 // partial slot

        float rowS = rowPart[p * NB + i];
        float colS = colPart[p * NB + i];
        #pragma unroll
        for (int o = 1; o < 32; o <<= 1) {
            rowS += __shfl_xor(rowS, o, 64);
            colS += __shfl_xor(colS, o, 64);
        }

        float contrib = 0.f;
        if (p == 0) {   // lanes 0 and 32 (rows i, i+1)
            const float d     = diag[i];
            const float lse_r = INV_T + __builtin_amdgcn_logf(rowS) * LN2;
            const float lse_c = INV_T + __builtin_amdgcn_logf(colS) * LN2;
            const float lpr = d - lse_r;
            const float lpc = d - lse_c;
            const float pp  = __builtin_amdgcn_exp2f(lpr * LOG2E);
            const float om  = 1.f - pp;
            contrib = om * om * (-lpr - lpc) * (0.5f / (float)NB);
        }
        contrib += __shfl_xor(contrib, 32, 64);          // lane0 += lane32

        __shared__ float red[4];
        if (lane == 0) red[wid] = contrib;
        __syncthreads();
        if (threadIdx.x == 0)
            atomicAdd(out, red[0] + red[1] + red[2] + red[3]);
    }
}

// ------------------- fallback: original 3-kernel pipeline ------------------
__global__ __launch_bounds__(256)
void norm_kernel(const float* __restrict__ img, const float* __restrict__ txt,
                 __hip_bfloat16* __restrict__ imgB,
                 __hip_bfloat16* __restrict__ txtB,
                 float* __restrict__ diag, float* __restrict__ out)
{
    if (blockIdx.x == 0 && threadIdx.x == 0) out[0] = 0.f;
    norm_body(blockIdx.x * 4 + (threadIdx.x >> 6), threadIdx.x & 63,
              img, txt, imgB, txtB, diag);
}

__global__ __launch_bounds__(256)
void score_kernel(const __hip_bfloat16* __restrict__ imgB,
                  const __hip_bfloat16* __restrict__ txtB,
                  float* __restrict__ rowPart, float* __restrict__ colPart)
{
    __shared__ float sm[4][256];
    score_body(blockIdx.x, threadIdx.x >> 6, threadIdx.x & 63, sm,
               imgB, txtB, rowPart, colPart);
}

__global__ __launch_bounds__(256)
void finish_kernel(const float* __restrict__ rowPart,
                   const float* __restrict__ colPart,
                   const float* __restrict__ diag,
                   float* __restrict__ out)
{
    const int tg = blockIdx.x * 256 + threadIdx.x;   // 0..65535
    const int i  = tg >> 3;
    const int p  = threadIdx.x & 7;
    float rowS = 0.f, colS = 0.f;
    #pragma unroll
    for (int u = 0; u < 4; ++u) {
        rowS += rowPart[(p * 4 + u) * NB + i];
        colS += colPart[(p * 4 + u) * NB + i];
    }
    #pragma unroll
    for (int o = 1; o < 8; o <<= 1) {
        rowS += __shfl_xor(rowS, o, 64);
        colS += __shfl_xor(colS, o, 64);
    }
    float contrib = 0.f;
    if (p == 0) {
        const float d     = diag[i];
        const float lse_r = INV_T + __builtin_amdgcn_logf(rowS) * LN2;
        const float lse_c = INV_T + __builtin_amdgcn_logf(colS) * LN2;
        const float lpr = d - lse_r;
        const float lpc = d - lse_c;
        const float pp  = __builtin_amdgcn_exp2f(lpr * LOG2E);
        const float om  = 1.f - pp;
        contrib = om * om * (-lpr - lpc) * (0.5f / (float)NB);
    }
    #pragma unroll
    for (int o = 8; o < 64; o <<= 1) contrib += __shfl_xor(contrib, o, 64);
    __shared__ float red[4];
    if ((threadIdx.x & 63) == 0) red[threadIdx.x >> 6] = contrib;
    __syncthreads();
    if (threadIdx.x == 0)
        atomicAdd(out, red[0] + red[1] + red[2] + red[3]);
}

// ---------------------------------------------------------------------------
extern "C" void kernel_launch(void* const* d_in, const int* in_sizes, int n_in,
                              void* d_out, int out_size, void* d_ws, size_t ws_size,
                              hipStream_t stream)
{
    const float* img = (const float*)d_in[0];
    const float* txt = (const float*)d_in[1];

    char* ws = (char*)d_ws;
    __hip_bfloat16* imgB = (__hip_bfloat16*)(ws);                        // 1 MB
    __hip_bfloat16* txtB = (__hip_bfloat16*)(ws + (1u << 20));           // 1 MB
    float* diag    = (float*)(ws + (2u << 20));                          // 32 KB
    float* rowPart = (float*)(ws + (2u << 20) + (1u << 15));             // 1 MB
    float* colPart = (float*)(ws + (3u << 20) + (1u << 15));             // 1 MB
    float* outp    = (float*)d_out;

    void* args[] = {(void*)&img, (void*)&txt, (void*)&imgB, (void*)&txtB,
                    (void*)&diag, (void*)&rowPart, (void*)&colPart, (void*)&outp};
    hipError_t err = hipLaunchCooperativeKernel((void*)fused_kernel,
                                                dim3(1024), dim3(256),
                                                args, 0, stream);
    if (err != hipSuccess) {
        // occupancy-validation fallback: original 3-kernel pipeline
        norm_kernel<<<512, 256, 0, stream>>>(img, txt, imgB, txtB, diag, outp);
        score_kernel<<<1024, 256, 0, stream>>>(imgB, txtB, rowPart, colPart);
        finish_kernel<<<256, 256, 0, stream>>>(rowPart, colPart, diag, outp);
    }
}

// Round 4
// 161.553 us; speedup vs baseline: 1.5960x; 1.5960x over previous
//
#include <hip/hip_runtime.h>
#include <hip/hip_bf16.h>

// ---------------------------------------------------------------------------
// ContrastiveLoss: B=8192, D=64, fp32 inputs, scalar fp32 output.
// loss = mean_i[ w_i * (-(d_i - lse_row_i) - (d_i - lse_col_i)) ] / 2
//   w_i = (1 - exp(d_i - lse_row_i))^2,  d_i = (img_i . txt_i)/T (fp32 exact)
//   lse_row_i = M + ln( sum_j exp(s_ij - M) ),  M = 1/T  (fixed shift: |s|<=M
//   since both factors are unit vectors -> no max pass needed)
// Trick: imgB rows are pre-scaled by K1 = LOG2E/T and the MFMA C-operand is
// initialized to -K1, so the accumulator exits the matrix pipe as the exp2
// argument directly: acc = K1*dot - K1 = (s - M)*log2(e). Zero VALU fixup.
// History: r1/r2 proved inner work (atomics vs none) moves nothing; window =
// 41us harness fill + ~10us work + ~30us dispatch-boundary overhead. r3's
// cooperative grid.sync cost ~90us/sync (1024 cross-XCD spinners on one
// MALL line) -- mechanism dead, gap theory alive. This revision removes ONE
// boundary with a contention-free primitive: finish is fused into score as
// a last-32-blocks epilogue (threadfence + arrival counter; rank>=992 ->
// finisher; only 32 spinners, arriving last so spin ~= 0). Cross-XCD
// partial reads use agent-scope atomic loads (stale-L2 hazard, G16).
// norm (prior kernel, proven) zeroes counter + out.
// ---------------------------------------------------------------------------

#define NB 8192
#define ND 64
#define NBLK 1024          // score grid
#define NFIN 32            // finisher blocks
#define FIN_START (NBLK - NFIN)

constexpr float INV_T = 1.0f / 0.07f;                 // 14.2857...
constexpr float LOG2E = 1.4426950408889634f;
constexpr float LN2   = 0.6931471805599453f;
constexpr float K1    = INV_T * LOG2E;                // exp2 arg scale

typedef float  floatx4 __attribute__((ext_vector_type(4)));
typedef short  bf16x8  __attribute__((ext_vector_type(8)));
typedef short  shortx4 __attribute__((ext_vector_type(4)));

// --------------------------- kernel 1: normalize ---------------------------
// 512 blocks x 256 threads. Each wave handles 4 rows: 16 lanes per row, one
// float4 per lane (coalesced dwordx4). Fused 4-step butterfly reduces
// |x|^2, |t|^2, x.t together within each 16-lane group. imgB gets the
// K1-prescaled bf16 copy (A side), txtB the plain normalized bf16 (B side).
// Also zeroes out[0] and the arrival counter (workspace is poisoned).
__global__ __launch_bounds__(256)
void norm_kernel(const float* __restrict__ img, const float* __restrict__ txt,
                 __hip_bfloat16* __restrict__ imgB,
                 __hip_bfloat16* __restrict__ txtB,
                 float* __restrict__ diag,
                 int* __restrict__ counter,
                 float* __restrict__ out)
{
    if (blockIdx.x == 0 && threadIdx.x == 0) { out[0] = 0.f; *counter = 0; }

    const int lane = threadIdx.x & 63;
    const int gw   = blockIdx.x * 4 + (threadIdx.x >> 6);     // 0..2047
    const int sub  = lane >> 4;                               // row within wave
    const int c16  = lane & 15;                               // float4 slot
    const int row  = gw * 4 + sub;                            // 0..8191

    const floatx4 x = ((const floatx4*)img)[row * 16 + c16];
    const floatx4 t = ((const floatx4*)txt)[row * 16 + c16];
    float sx  = x[0]*x[0] + x[1]*x[1] + x[2]*x[2] + x[3]*x[3];
    float st  = t[0]*t[0] + t[1]*t[1] + t[2]*t[2] + t[3]*t[3];
    float sxt = x[0]*t[0] + x[1]*t[1] + x[2]*t[2] + x[3]*t[3];
    #pragma unroll
    for (int o = 1; o < 16; o <<= 1) {
        sx  += __shfl_xor(sx,  o, 64);
        st  += __shfl_xor(st,  o, 64);
        sxt += __shfl_xor(sxt, o, 64);
    }
    const float nx = fmaxf(sqrtf(sx), 1e-12f);
    const float nt = fmaxf(sqrtf(st), 1e-12f);
    shortx4 xb, tb;
    #pragma unroll
    for (int j = 0; j < 4; ++j) {
        __hip_bfloat16 hx = __float2bfloat16(x[j] / nx * K1);  // A pre-scaled
        __hip_bfloat16 ht = __float2bfloat16(t[j] / nt);
        xb[j] = *reinterpret_cast<const short*>(&hx);
        tb[j] = *reinterpret_cast<const short*>(&ht);
    }
    ((shortx4*)imgB)[row * 16 + c16] = xb;                    // 8B coalesced
    ((shortx4*)txtB)[row * 16 + c16] = tb;
    if (c16 == 0) diag[row] = sxt / (nx * nt) * INV_T;        // exact fp32 diag
}

// ------------------ kernel 2: streamed score + fused finish ----------------
// Score part (unchanged from r2, proven): block b: chunk = b&31 (256 cols,
// shared by the 4 waves -> B loads hit L1), strip = (b>>5)*4 + wid (64
// rows/wave). A-fragments live in registers across the whole tile loop;
// next tile's B software-prefetched (branchless wrap). Per 16x16 tile: 2
// chained MFMAs (K=64, C init = -K1) x 4 row-tiles, 16 exp2 straight off
// the accumulator, row partials in registers, col partial via depth-4 tree
// + 2 shuffles -> LDS slot. Rows exit via butterfly reduce-scatter (15
// shuffles) -> plain unique-writer stores to rowPart[32][8192]; cols via
// LDS combine -> coalesced store to colPart[32][8192].
// Finish part: threadfence + arrival counter; the last 32 blocks to arrive
// (rank >= 992) each finish 256 rows: 64 agent-scope atomic loads of the
// cross-XCD partials, lse/focal math, wave+block reduce, one atomicAdd.
// mfma_f32_16x16x32_bf16 layouts (HW-verified):
//   A: lane holds A[m=lane&15][k=(lane>>4)*8 + j], j=0..7  (8 contig bf16)
//   B: lane holds B[n=lane&15][k=(lane>>4)*8 + j]          (NT layout)
//   C/D: col = lane&15, row = (lane>>4)*4 + r
__global__ __launch_bounds__(256)
void score_finish_kernel(const __hip_bfloat16* __restrict__ imgB,
                         const __hip_bfloat16* __restrict__ txtB,
                         float* __restrict__ rowPart,   // [32][8192] chunk-major
                         float* __restrict__ colPart,   // [32][8192] strip4-major
                         const float* __restrict__ diag,
                         int* __restrict__ counter,
                         float* __restrict__ out)
{
    const int wid   = threadIdx.x >> 6;
    const int lane  = threadIdx.x & 63;
    const int chunk = blockIdx.x & 31;        // cols chunk*256..+255
    const int sgrp  = blockIdx.x >> 5;        // strip group 0..31
    const int strip = sgrp * 4 + wid;         // rows strip*64..+63
    const int m = lane & 15;
    const int q = lane >> 4;

    __shared__ float sm[4][256];              // per-wave column partials

    const bf16x8* __restrict__ A  = (const bf16x8*)imgB;  // units of 8 elems
    const bf16x8* __restrict__ Bp = (const bf16x8*)txtB;

    const int rowbase = strip * 64;
    bf16x8 a[4][2];
    #pragma unroll
    for (int it = 0; it < 4; ++it) {
        const int r = rowbase + it * 16 + m;
        a[it][0] = A[r * 8 + q];        // k = q*8 .. q*8+7
        a[it][1] = A[r * 8 + 4 + q];    // k = 32 + q*8 ..
    }

    const int colbase = chunk * 256 + m;      // this lane's t=0 column
    bf16x8 b0 = Bp[colbase * 8 + q];
    bf16x8 b1 = Bp[colbase * 8 + 4 + q];

    float rs[16];
    #pragma unroll
    for (int i = 0; i < 16; ++i) rs[i] = 0.f;

    const floatx4 NEGK = {-K1, -K1, -K1, -K1};   // bakes the -M shift in

    #pragma unroll 2
    for (int t = 0; t < 16; ++t) {
        // prefetch next tile's B (t=15 wraps to t=0: harmless, avoids branch)
        const int nn = colbase + (((t + 1) & 15) << 4);
        const bf16x8 pb0 = Bp[nn * 8 + q];
        const bf16x8 pb1 = Bp[nn * 8 + 4 + q];

        float csp[4];
        #pragma unroll
        for (int it = 0; it < 4; ++it) {
            floatx4 z   = __builtin_amdgcn_mfma_f32_16x16x32_bf16(a[it][0], b0, NEGK, 0, 0, 0);
            floatx4 acc = __builtin_amdgcn_mfma_f32_16x16x32_bf16(a[it][1], b1, z,    0, 0, 0);
            // acc == (s - M) * log2(e) already
            const float e0 = __builtin_amdgcn_exp2f(acc[0]);
            const float e1 = __builtin_amdgcn_exp2f(acc[1]);
            const float e2 = __builtin_amdgcn_exp2f(acc[2]);
            const float e3 = __builtin_amdgcn_exp2f(acc[3]);
            rs[it * 4 + 0] += e0;
            rs[it * 4 + 1] += e1;
            rs[it * 4 + 2] += e2;
            rs[it * 4 + 3] += e3;
            csp[it] = (e0 + e1) + (e2 + e3);     // depth-2 tree
        }
        float cs = (csp[0] + csp[1]) + (csp[2] + csp[3]);
        // combine the 4 quads -> col sum over this wave's 64 rows
        cs += __shfl_xor(cs, 16, 64);
        cs += __shfl_xor(cs, 32, 64);
        if (q == 0) sm[wid][(t << 4) + m] = cs;   // unique LDS slot, no sync yet
        b0 = pb0; b1 = pb1;
    }

    // Butterfly reduce-scatter over the 16 m-lanes (per q-group):
    // after stage d, lanes whose bit log2(d) of m is set own the upper-half
    // indices. Final: lane m holds the full strip-row sum for idx == m.
#define RS_STAGE(d)                                                     \
    {                                                                   \
        const bool hi = (m & (d)) != 0;                                 \
        _Pragma("unroll")                                               \
        for (int j = 0; j < (d); ++j) {                                 \
            const float va = rs[j], vb = rs[j + (d)];                   \
            const float send = hi ? va : vb;                            \
            const float recv = __shfl_xor(send, (d), 64);               \
            rs[j] = (hi ? vb : va) + recv;                              \
        }                                                               \
    }
    RS_STAGE(8)
    RS_STAGE(4)
    RS_STAGE(2)
    RS_STAGE(1)
#undef RS_STAGE

    // idx == m: it = m>>2, r = m&3; all 64 lanes hit 64 distinct rows.
    // Plain store: (chunk,row) has exactly one writer wave.
    const int row = rowbase + ((m >> 2) << 4) + (q << 2) + (m & 3);
    rowPart[chunk * NB + row] = rs[0];

    // Column combine across the block's 4 waves (strips) -> plain store.
    __syncthreads();
    {
        const int j = threadIdx.x;             // 0..255
        const float v = (sm[0][j] + sm[1][j]) + (sm[2][j] + sm[3][j]);
        colPart[sgrp * NB + chunk * 256 + j] = v;  // coalesced, unique writer
    }

    // ---------------- fused finish: last-NFIN-blocks epilogue --------------
    __shared__ int s_rank;
    __threadfence();                 // release this block's partial stores
    __syncthreads();                 // all threads' fences precede the add
    if (threadIdx.x == 0) {
        const int r = atomicAdd(counter, 1);     // device-scope arrival
        s_rank = r;
        if (r >= FIN_START) {
            // last arrivals spin: <=NFIN spinners, expected near-zero wait
            while (__hip_atomic_load(counter, __ATOMIC_RELAXED,
                                     __HIP_MEMORY_SCOPE_AGENT) < NBLK)
                __builtin_amdgcn_s_sleep(8);
        }
    }
    __syncthreads();
    const int rank = s_rank;
    if (rank < FIN_START) return;    // 992 blocks exit, freeing CUs
    __threadfence();                 // acquire side

    // finisher (rank-FIN_START) handles rows fi*256 .. +255, one per thread.
    // Agent-scope atomic loads: partials were written by blocks on other
    // XCDs; plain loads could hit a stale per-XCD L2 line (G16 hazard).
    const int i = (rank - FIN_START) * 256 + threadIdx.x;   // 0..8191
    float rowS = 0.f, colS = 0.f;
    #pragma unroll 8
    for (int c = 0; c < 32; ++c)
        rowS += __hip_atomic_load(&rowPart[c * NB + i], __ATOMIC_RELAXED,
                                  __HIP_MEMORY_SCOPE_AGENT);
    #pragma unroll 8
    for (int c = 0; c < 32; ++c)
        colS += __hip_atomic_load(&colPart[c * NB + i], __ATOMIC_RELAXED,
                                  __HIP_MEMORY_SCOPE_AGENT);

    const float d     = diag[i];     // produced by the PRIOR kernel: visible
    const float lse_r = INV_T + __builtin_amdgcn_logf(rowS) * LN2;
    const float lse_c = INV_T + __builtin_amdgcn_logf(colS) * LN2;
    const float lpr = d - lse_r;
    const float lpc = d - lse_c;
    const float pp  = __builtin_amdgcn_exp2f(lpr * LOG2E);
    const float om  = 1.f - pp;
    float contrib = om * om * (-lpr - lpc) * (0.5f / (float)NB);

    #pragma unroll
    for (int o = 1; o < 64; o <<= 1) contrib += __shfl_xor(contrib, o, 64);
    __shared__ float red[4];
    if (lane == 0) red[wid] = contrib;
    __syncthreads();
    if (threadIdx.x == 0)
        atomicAdd(out, red[0] + red[1] + red[2] + red[3]);
}

// ---------------------------------------------------------------------------
extern "C" void kernel_launch(void* const* d_in, const int* in_sizes, int n_in,
                              void* d_out, int out_size, void* d_ws, size_t ws_size,
                              hipStream_t stream)
{
    const float* img = (const float*)d_in[0];
    const float* txt = (const float*)d_in[1];

    char* ws = (char*)d_ws;
    __hip_bfloat16* imgB = (__hip_bfloat16*)(ws);                        // 1 MB
    __hip_bfloat16* txtB = (__hip_bfloat16*)(ws + (1u << 20));           // 1 MB
    float* diag    = (float*)(ws + (2u << 20));                          // 32 KB
    float* rowPart = (float*)(ws + (2u << 20) + (1u << 15));             // 1 MB
    float* colPart = (float*)(ws + (3u << 20) + (1u << 15));             // 1 MB
    int*   counter = (int*)  (ws + (4u << 20) + (1u << 15));             // 4 B
    float* outp    = (float*)d_out;

    norm_kernel<<<512, 256, 0, stream>>>(img, txt, imgB, txtB, diag, counter, outp);
    score_finish_kernel<<<NBLK, 256, 0, stream>>>(imgB, txtB, rowPart, colPart,
                                                  diag, counter, outp);
}

// Round 5
// 93.029 us; speedup vs baseline: 2.7715x; 1.7366x over previous
//
#include <hip/hip_runtime.h>
#include <hip/hip_bf16.h>

// ---------------------------------------------------------------------------
// ContrastiveLoss: B=8192, D=64, fp32 inputs, scalar fp32 output.
// loss = mean_i[ w_i * (-(d_i - lse_row_i) - (d_i - lse_col_i)) ] / 2
//   w_i = (1 - exp(d_i - lse_row_i))^2,  d_i = (img_i . txt_i)/T (fp32 exact)
//   lse_row_i = M + ln( sum_j exp(s_ij - M) ),  M = 1/T  (fixed shift: |s|<=M
//   since both factors are unit vectors -> no max pass needed)
// Trick: imgB rows are pre-scaled by K1 = LOG2E/T and the MFMA C-operand is
// initialized to -K1, so the accumulator exits the matrix pipe as the exp2
// argument directly: acc = K1*dot - K1 = (s - M)*log2(e). Zero VALU fixup.
// History: r1/r2: inner work is free; window = 41us harness fill + ~10us
// work + ~30us dispatch-boundary overhead. r3: grid.sync ~90us/sync. r4:
// last-32-blocks fused finish was CORRECT but __threadfence in every wave
// cost ~105us -- device-scope fences lower to L2 writeback (buffer_wbl2)
// because per-XCD L2s are non-coherent; 4096 waves x ~25ns serialized.
// This revision: SAME fused-finish structure, ZERO fences. Partials are
// written with agent-scope RELAXED atomic stores (write-through, commit at
// the MALL coherence point -> no dirty L2 lines to flush). Each wave drains
// its own stores with s_waitcnt vmcnt(0); __syncthreads makes that
// block-wide; counter bump is a RELAXED agent fetch_add. Finishers read
// partials with agent-scope RELAXED atomic loads (bypass possibly-stale
// L2; validated correct in r4).
// ---------------------------------------------------------------------------

#define NB 8192
#define ND 64
#define NBLK 1024          // score grid
#define NFIN 32            // finisher blocks
#define FIN_START (NBLK - NFIN)

constexpr float INV_T = 1.0f / 0.07f;                 // 14.2857...
constexpr float LOG2E = 1.4426950408889634f;
constexpr float LN2   = 0.6931471805599453f;
constexpr float K1    = INV_T * LOG2E;                // exp2 arg scale

typedef float  floatx4 __attribute__((ext_vector_type(4)));
typedef short  bf16x8  __attribute__((ext_vector_type(8)));
typedef short  shortx4 __attribute__((ext_vector_type(4)));

// --------------------------- kernel 1: normalize ---------------------------
// 512 blocks x 256 threads. Each wave handles 4 rows: 16 lanes per row, one
// float4 per lane (coalesced dwordx4). Fused 4-step butterfly reduces
// |x|^2, |t|^2, x.t together within each 16-lane group. imgB gets the
// K1-prescaled bf16 copy (A side), txtB the plain normalized bf16 (B side).
// Also zeroes out[0] and the arrival counter (workspace is poisoned).
__global__ __launch_bounds__(256)
void norm_kernel(const float* __restrict__ img, const float* __restrict__ txt,
                 __hip_bfloat16* __restrict__ imgB,
                 __hip_bfloat16* __restrict__ txtB,
                 float* __restrict__ diag,
                 int* __restrict__ counter,
                 float* __restrict__ out)
{
    if (blockIdx.x == 0 && threadIdx.x == 0) { out[0] = 0.f; *counter = 0; }

    const int lane = threadIdx.x & 63;
    const int gw   = blockIdx.x * 4 + (threadIdx.x >> 6);     // 0..2047
    const int sub  = lane >> 4;                               // row within wave
    const int c16  = lane & 15;                               // float4 slot
    const int row  = gw * 4 + sub;                            // 0..8191

    const floatx4 x = ((const floatx4*)img)[row * 16 + c16];
    const floatx4 t = ((const floatx4*)txt)[row * 16 + c16];
    float sx  = x[0]*x[0] + x[1]*x[1] + x[2]*x[2] + x[3]*x[3];
    float st  = t[0]*t[0] + t[1]*t[1] + t[2]*t[2] + t[3]*t[3];
    float sxt = x[0]*t[0] + x[1]*t[1] + x[2]*t[2] + x[3]*t[3];
    #pragma unroll
    for (int o = 1; o < 16; o <<= 1) {
        sx  += __shfl_xor(sx,  o, 64);
        st  += __shfl_xor(st,  o, 64);
        sxt += __shfl_xor(sxt, o, 64);
    }
    const float nx = fmaxf(sqrtf(sx), 1e-12f);
    const float nt = fmaxf(sqrtf(st), 1e-12f);
    shortx4 xb, tb;
    #pragma unroll
    for (int j = 0; j < 4; ++j) {
        __hip_bfloat16 hx = __float2bfloat16(x[j] / nx * K1);  // A pre-scaled
        __hip_bfloat16 ht = __float2bfloat16(t[j] / nt);
        xb[j] = *reinterpret_cast<const short*>(&hx);
        tb[j] = *reinterpret_cast<const short*>(&ht);
    }
    ((shortx4*)imgB)[row * 16 + c16] = xb;                    // 8B coalesced
    ((shortx4*)txtB)[row * 16 + c16] = tb;
    if (c16 == 0) diag[row] = sxt / (nx * nt) * INV_T;        // exact fp32 diag
}

// ------------------ kernel 2: streamed score + fused finish ----------------
// Score part (unchanged, proven): block b: chunk = b&31 (256 cols, shared by
// the 4 waves -> B loads hit L1), strip = (b>>5)*4 + wid (64 rows/wave).
// A-fragments live in registers across the whole tile loop; next tile's B
// software-prefetched (branchless wrap). Per 16x16 tile: 2 chained MFMAs
// (K=64, C init = -K1) x 4 row-tiles, 16 exp2 straight off the accumulator,
// row partials in registers, col partial via depth-4 tree + 2 shuffles ->
// LDS slot. Rows exit via butterfly reduce-scatter (15 shuffles).
// Partials leave as AGENT-scope RELAXED atomic stores (write-through to the
// MALL: cross-XCD visible with NO fence). Epilogue: vmcnt(0) drain +
// __syncthreads + RELAXED agent arrival counter; last NFIN blocks finish
// 256 rows each via agent-scope RELAXED atomic loads.
// mfma_f32_16x16x32_bf16 layouts (HW-verified):
//   A: lane holds A[m=lane&15][k=(lane>>4)*8 + j], j=0..7  (8 contig bf16)
//   B: lane holds B[n=lane&15][k=(lane>>4)*8 + j]          (NT layout)
//   C/D: col = lane&15, row = (lane>>4)*4 + r
__global__ __launch_bounds__(256)
void score_finish_kernel(const __hip_bfloat16* __restrict__ imgB,
                         const __hip_bfloat16* __restrict__ txtB,
                         float* __restrict__ rowPart,   // [32][8192] chunk-major
                         float* __restrict__ colPart,   // [32][8192] strip4-major
                         const float* __restrict__ diag,
                         int* __restrict__ counter,
                         float* __restrict__ out)
{
    const int wid   = threadIdx.x >> 6;
    const int lane  = threadIdx.x & 63;
    const int chunk = blockIdx.x & 31;        // cols chunk*256..+255
    const int sgrp  = blockIdx.x >> 5;        // strip group 0..31
    const int strip = sgrp * 4 + wid;         // rows strip*64..+63
    const int m = lane & 15;
    const int q = lane >> 4;

    __shared__ float sm[4][256];              // per-wave column partials

    const bf16x8* __restrict__ A  = (const bf16x8*)imgB;  // units of 8 elems
    const bf16x8* __restrict__ Bp = (const bf16x8*)txtB;

    const int rowbase = strip * 64;
    bf16x8 a[4][2];
    #pragma unroll
    for (int it = 0; it < 4; ++it) {
        const int r = rowbase + it * 16 + m;
        a[it][0] = A[r * 8 + q];        // k = q*8 .. q*8+7
        a[it][1] = A[r * 8 + 4 + q];    // k = 32 + q*8 ..
    }

    const int colbase = chunk * 256 + m;      // this lane's t=0 column
    bf16x8 b0 = Bp[colbase * 8 + q];
    bf16x8 b1 = Bp[colbase * 8 + 4 + q];

    float rs[16];
    #pragma unroll
    for (int i = 0; i < 16; ++i) rs[i] = 0.f;

    const floatx4 NEGK = {-K1, -K1, -K1, -K1};   // bakes the -M shift in

    #pragma unroll 2
    for (int t = 0; t < 16; ++t) {
        // prefetch next tile's B (t=15 wraps to t=0: harmless, avoids branch)
        const int nn = colbase + (((t + 1) & 15) << 4);
        const bf16x8 pb0 = Bp[nn * 8 + q];
        const bf16x8 pb1 = Bp[nn * 8 + 4 + q];

        float csp[4];
        #pragma unroll
        for (int it = 0; it < 4; ++it) {
            floatx4 z   = __builtin_amdgcn_mfma_f32_16x16x32_bf16(a[it][0], b0, NEGK, 0, 0, 0);
            floatx4 acc = __builtin_amdgcn_mfma_f32_16x16x32_bf16(a[it][1], b1, z,    0, 0, 0);
            // acc == (s - M) * log2(e) already
            const float e0 = __builtin_amdgcn_exp2f(acc[0]);
            const float e1 = __builtin_amdgcn_exp2f(acc[1]);
            const float e2 = __builtin_amdgcn_exp2f(acc[2]);
            const float e3 = __builtin_amdgcn_exp2f(acc[3]);
            rs[it * 4 + 0] += e0;
            rs[it * 4 + 1] += e1;
            rs[it * 4 + 2] += e2;
            rs[it * 4 + 3] += e3;
            csp[it] = (e0 + e1) + (e2 + e3);     // depth-2 tree
        }
        float cs = (csp[0] + csp[1]) + (csp[2] + csp[3]);
        // combine the 4 quads -> col sum over this wave's 64 rows
        cs += __shfl_xor(cs, 16, 64);
        cs += __shfl_xor(cs, 32, 64);
        if (q == 0) sm[wid][(t << 4) + m] = cs;   // unique LDS slot, no sync yet
        b0 = pb0; b1 = pb1;
    }

    // Butterfly reduce-scatter over the 16 m-lanes (per q-group):
    // after stage d, lanes whose bit log2(d) of m is set own the upper-half
    // indices. Final: lane m holds the full strip-row sum for idx == m.
#define RS_STAGE(d)                                                     \
    {                                                                   \
        const bool hi = (m & (d)) != 0;                                 \
        _Pragma("unroll")                                               \
        for (int j = 0; j < (d); ++j) {                                 \
            const float va = rs[j], vb = rs[j + (d)];                   \
            const float send = hi ? va : vb;                            \
            const float recv = __shfl_xor(send, (d), 64);               \
            rs[j] = (hi ? vb : va) + recv;                              \
        }                                                               \
    }
    RS_STAGE(8)
    RS_STAGE(4)
    RS_STAGE(2)
    RS_STAGE(1)
#undef RS_STAGE

    // idx == m: it = m>>2, r = m&3; all 64 lanes hit 64 distinct rows.
    // AGENT-scope write-through store: cross-XCD visible, no fence needed.
    const int row = rowbase + ((m >> 2) << 4) + (q << 2) + (m & 3);
    __hip_atomic_store(&rowPart[chunk * NB + row], rs[0],
                       __ATOMIC_RELAXED, __HIP_MEMORY_SCOPE_AGENT);

    // Column combine across the block's 4 waves (strips) -> write-through.
    __syncthreads();
    {
        const int j = threadIdx.x;             // 0..255
        const float v = (sm[0][j] + sm[1][j]) + (sm[2][j] + sm[3][j]);
        __hip_atomic_store(&colPart[sgrp * NB + chunk * 256 + j], v,
                           __ATOMIC_RELAXED, __HIP_MEMORY_SCOPE_AGENT);
    }

    // ---------------- fused finish: last-NFIN-blocks epilogue --------------
    // NO __threadfence (that was r4's 105us: buffer_wbl2 per wave). The
    // write-through stores above commit at the MALL; vmcnt(0) = this wave's
    // stores are complete there; __syncthreads = true for all 4 waves.
    __shared__ int s_rank;
    asm volatile("s_waitcnt vmcnt(0)" ::: "memory");
    __syncthreads();
    if (threadIdx.x == 0) {
        const int r = __hip_atomic_fetch_add(counter, 1, __ATOMIC_RELAXED,
                                             __HIP_MEMORY_SCOPE_AGENT);
        s_rank = r;
        if (r >= FIN_START) {
            // last arrivals spin: <=NFIN spinners, expected near-zero wait
            while (__hip_atomic_load(counter, __ATOMIC_RELAXED,
                                     __HIP_MEMORY_SCOPE_AGENT) < NBLK)
                __builtin_amdgcn_s_sleep(8);
        }
    }
    __syncthreads();
    const int rank = s_rank;
    if (rank < FIN_START) return;    // 992 blocks exit, freeing CUs

    // finisher (rank-FIN_START) handles rows fi*256 .. +255, one per thread.
    // Agent-scope atomic loads: partials were written by blocks on other
    // XCDs; plain loads could hit a stale per-XCD L2 line (G16 hazard).
    const int i = (rank - FIN_START) * 256 + threadIdx.x;   // 0..8191
    float rowS = 0.f, colS = 0.f;
    #pragma unroll 8
    for (int c = 0; c < 32; ++c)
        rowS += __hip_atomic_load(&rowPart[c * NB + i], __ATOMIC_RELAXED,
                                  __HIP_MEMORY_SCOPE_AGENT);
    #pragma unroll 8
    for (int c = 0; c < 32; ++c)
        colS += __hip_atomic_load(&colPart[c * NB + i], __ATOMIC_RELAXED,
                                  __HIP_MEMORY_SCOPE_AGENT);

    const float d     = diag[i];     // produced by the PRIOR kernel: visible
    const float lse_r = INV_T + __builtin_amdgcn_logf(rowS) * LN2;
    const float lse_c = INV_T + __builtin_amdgcn_logf(colS) * LN2;
    const float lpr = d - lse_r;
    const float lpc = d - lse_c;
    const float pp  = __builtin_amdgcn_exp2f(lpr * LOG2E);
    const float om  = 1.f - pp;
    float contrib = om * om * (-lpr - lpc) * (0.5f / (float)NB);

    #pragma unroll
    for (int o = 1; o < 64; o <<= 1) contrib += __shfl_xor(contrib, o, 64);
    __shared__ float red[4];
    if (lane == 0) red[wid] = contrib;
    __syncthreads();
    if (threadIdx.x == 0)
        atomicAdd(out, red[0] + red[1] + red[2] + red[3]);
}

// ---------------------------------------------------------------------------
extern "C" void kernel_launch(void* const* d_in, const int* in_sizes, int n_in,
                              void* d_out, int out_size, void* d_ws, size_t ws_size,
                              hipStream_t stream)
{
    const float* img = (const float*)d_in[0];
    const float* txt = (const float*)d_in[1];

    char* ws = (char*)d_ws;
    __hip_bfloat16* imgB = (__hip_bfloat16*)(ws);                        // 1 MB
    __hip_bfloat16* txtB = (__hip_bfloat16*)(ws + (1u << 20));           // 1 MB
    float* diag    = (float*)(ws + (2u << 20));                          // 32 KB
    float* rowPart = (float*)(ws + (2u << 20) + (1u << 15));             // 1 MB
    float* colPart = (float*)(ws + (3u << 20) + (1u << 15));             // 1 MB
    int*   counter = (int*)  (ws + (4u << 20) + (1u << 15));             // 4 B
    float* outp    = (float*)d_out;

    norm_kernel<<<512, 256, 0, stream>>>(img, txt, imgB, txtB, diag, counter, outp);
    score_finish_kernel<<<NBLK, 256, 0, stream>>>(imgB, txtB, rowPart, colPart,
                                                  diag, counter, outp);
}

// Round 6
// 85.419 us; speedup vs baseline: 3.0185x; 1.0891x over previous
//
#include <hip/hip_runtime.h>
#include <hip/hip_bf16.h>

// ---------------------------------------------------------------------------
// ContrastiveLoss: B=8192, D=64, fp32 inputs, scalar fp32 output.
// loss = mean_i[ w_i * (-(d_i - lse_row_i) - (d_i - lse_col_i)) ] / 2
//   w_i = (1 - exp(d_i - lse_row_i))^2,  d_i = (img_i . txt_i)/T (fp32 exact)
//   lse_row_i = M + ln( sum_j exp(s_ij - M) ),  M = 1/T  (fixed shift: |s|<=M
//   since both factors are unit vectors -> no max pass needed)
// Trick: imgB rows are pre-scaled by K1 = LOG2E/T and the MFMA C-operand is
// initialized to -K1, so the accumulator exits the matrix pipe as the exp2
// argument directly: acc = K1*dot - K1 = (s - M)*log2(e). Zero VALU fixup.
//
// FINAL STRUCTURE (reverted to round-2 optimum). Session evidence:
//   r1 83.1 (bulk atomics) ~= r2 84.7 (arrays)  -> inner dataflow is free
//   r3 257.8: grid.sync ~90us/sync (1024 cross-XCD spinners -> MALL)
//   r4 161.5: __threadfence/wave ~105us (L2 writeback, non-coherent XCD L2s)
//   r5 93.0: fence-free fused finish correct but neutral-to-worse
//            (serial finisher tail repays the saved launch boundary)
// Structural floor: 268MB harness poison fill ~41-44us (76-82% HBM peak,
// itself at roofline) + ~10-12us required kernel work (score is TRANS+L2
// bound) + ~30us harness reset dispatches / launch gaps insensitive to
// kernel structure (proven by r1/r2/r5 equivalence). No remaining theory
// predicts >3%.
// ---------------------------------------------------------------------------

#define NB 8192
#define ND 64

constexpr float INV_T = 1.0f / 0.07f;                 // 14.2857...
constexpr float LOG2E = 1.4426950408889634f;
constexpr float LN2   = 0.6931471805599453f;
constexpr float K1    = INV_T * LOG2E;                // exp2 arg scale

typedef float  floatx4 __attribute__((ext_vector_type(4)));
typedef short  bf16x8  __attribute__((ext_vector_type(8)));
typedef short  shortx4 __attribute__((ext_vector_type(4)));

// --------------------------- kernel 1: normalize ---------------------------
// 512 blocks x 256 threads. Each wave handles 4 rows: 16 lanes per row, one
// float4 per lane (coalesced dwordx4). Fused 4-step butterfly reduces
// |x|^2, |t|^2, x.t together within each 16-lane group. imgB gets the
// K1-prescaled bf16 copy (A side), txtB the plain normalized bf16 (B side).
// Also zeroes out[0] (finish accumulates into it atomically).
__global__ __launch_bounds__(256)
void norm_kernel(const float* __restrict__ img, const float* __restrict__ txt,
                 __hip_bfloat16* __restrict__ imgB,
                 __hip_bfloat16* __restrict__ txtB,
                 float* __restrict__ diag,
                 float* __restrict__ out)
{
    if (blockIdx.x == 0 && threadIdx.x == 0) out[0] = 0.f;    // replaces memset

    const int lane = threadIdx.x & 63;
    const int gw   = blockIdx.x * 4 + (threadIdx.x >> 6);     // 0..2047
    const int sub  = lane >> 4;                               // row within wave
    const int c16  = lane & 15;                               // float4 slot
    const int row  = gw * 4 + sub;                            // 0..8191

    const floatx4 x = ((const floatx4*)img)[row * 16 + c16];
    const floatx4 t = ((const floatx4*)txt)[row * 16 + c16];
    float sx  = x[0]*x[0] + x[1]*x[1] + x[2]*x[2] + x[3]*x[3];
    float st  = t[0]*t[0] + t[1]*t[1] + t[2]*t[2] + t[3]*t[3];
    float sxt = x[0]*t[0] + x[1]*t[1] + x[2]*t[2] + x[3]*t[3];
    #pragma unroll
    for (int o = 1; o < 16; o <<= 1) {
        sx  += __shfl_xor(sx,  o, 64);
        st  += __shfl_xor(st,  o, 64);
        sxt += __shfl_xor(sxt, o, 64);
    }
    const float nx = fmaxf(sqrtf(sx), 1e-12f);
    const float nt = fmaxf(sqrtf(st), 1e-12f);
    shortx4 xb, tb;
    #pragma unroll
    for (int j = 0; j < 4; ++j) {
        __hip_bfloat16 hx = __float2bfloat16(x[j] / nx * K1);  // A pre-scaled
        __hip_bfloat16 ht = __float2bfloat16(t[j] / nt);
        xb[j] = *reinterpret_cast<const short*>(&hx);
        tb[j] = *reinterpret_cast<const short*>(&ht);
    }
    ((shortx4*)imgB)[row * 16 + c16] = xb;                    // 8B coalesced
    ((shortx4*)txtB)[row * 16 + c16] = tb;
    if (c16 == 0) diag[row] = sxt / (nx * nt) * INV_T;        // exact fp32 diag
}

// ----------------------- kernel 2: streamed score pass ---------------------
// Block b: chunk = b&31 (256 cols, shared by all 4 waves -> B loads are L1
// hits), strip = (b>>5)*4 + wid (64 rows per wave). A-fragments stay in
// registers across the whole tile loop; next tile's B is software-prefetched
// (branchless wraparound). Per 16x16 tile: 2 chained MFMAs (K=64, C init =
// -K1) x 4 row-tiles, 16 exp2 straight off the accumulator, row partials in
// registers, col partial via depth-4 tree + 2 shuffles -> LDS slot.
// After the loop:
//   rows: butterfly reduce-scatter (d=8,4,2,1; 15 shuffles) leaves lane
//         (m,q) holding the full 256-col partial of one row -> one plain
//         64-lane store to rowPart[chunk][64 rows]   (unique writer).
//   cols: __syncthreads, then 256 threads sum the 4 waves' LDS partials ->
//         one coalesced 1 KB store to colPart[b>>5][chunk*256..+255].
// mfma_f32_16x16x32_bf16 layouts (HW-verified):
//   A: lane holds A[m=lane&15][k=(lane>>4)*8 + j], j=0..7  (8 contig bf16)
//   B: lane holds B[n=lane&15][k=(lane>>4)*8 + j]          (NT layout)
//   C/D: col = lane&15, row = (lane>>4)*4 + r
__global__ __launch_bounds__(256)
void score_kernel(const __hip_bfloat16* __restrict__ imgB,
                  const __hip_bfloat16* __restrict__ txtB,
                  float* __restrict__ rowPart,   // [32][8192]  chunk-major
                  float* __restrict__ colPart)   // [32][8192]  strip4-major
{
    const int wid   = threadIdx.x >> 6;
    const int lane  = threadIdx.x & 63;
    const int chunk = blockIdx.x & 31;        // cols chunk*256..+255
    const int sgrp  = blockIdx.x >> 5;        // strip group 0..31
    const int strip = sgrp * 4 + wid;         // rows strip*64..+63
    const int m = lane & 15;
    const int q = lane >> 4;

    __shared__ float sm[4][256];              // per-wave column partials

    const bf16x8* __restrict__ A  = (const bf16x8*)imgB;  // units of 8 elems
    const bf16x8* __restrict__ Bp = (const bf16x8*)txtB;

    const int rowbase = strip * 64;
    bf16x8 a[4][2];
    #pragma unroll
    for (int it = 0; it < 4; ++it) {
        const int r = rowbase + it * 16 + m;
        a[it][0] = A[r * 8 + q];        // k = q*8 .. q*8+7
        a[it][1] = A[r * 8 + 4 + q];    // k = 32 + q*8 ..
    }

    const int colbase = chunk * 256 + m;      // this lane's t=0 column
    bf16x8 b0 = Bp[colbase * 8 + q];
    bf16x8 b1 = Bp[colbase * 8 + 4 + q];

    float rs[16];
    #pragma unroll
    for (int i = 0; i < 16; ++i) rs[i] = 0.f;

    const floatx4 NEGK = {-K1, -K1, -K1, -K1};   // bakes the -M shift in

    #pragma unroll 2
    for (int t = 0; t < 16; ++t) {
        // prefetch next tile's B (t=15 wraps to t=0: harmless, avoids branch)
        const int nn = colbase + (((t + 1) & 15) << 4);
        const bf16x8 pb0 = Bp[nn * 8 + q];
        const bf16x8 pb1 = Bp[nn * 8 + 4 + q];

        float csp[4];
        #pragma unroll
        for (int it = 0; it < 4; ++it) {
            floatx4 z   = __builtin_amdgcn_mfma_f32_16x16x32_bf16(a[it][0], b0, NEGK, 0, 0, 0);
            floatx4 acc = __builtin_amdgcn_mfma_f32_16x16x32_bf16(a[it][1], b1, z,    0, 0, 0);
            // acc == (s - M) * log2(e) already
            const float e0 = __builtin_amdgcn_exp2f(acc[0]);
            const float e1 = __builtin_amdgcn_exp2f(acc[1]);
            const float e2 = __builtin_amdgcn_exp2f(acc[2]);
            const float e3 = __builtin_amdgcn_exp2f(acc[3]);
            rs[it * 4 + 0] += e0;
            rs[it * 4 + 1] += e1;
            rs[it * 4 + 2] += e2;
            rs[it * 4 + 3] += e3;
            csp[it] = (e0 + e1) + (e2 + e3);     // depth-2 tree
        }
        float cs = (csp[0] + csp[1]) + (csp[2] + csp[3]);
        // combine the 4 quads -> col sum over this wave's 64 rows
        cs += __shfl_xor(cs, 16, 64);
        cs += __shfl_xor(cs, 32, 64);
        if (q == 0) sm[wid][(t << 4) + m] = cs;   // unique LDS slot, no sync yet
        b0 = pb0; b1 = pb1;
    }

    // Butterfly reduce-scatter over the 16 m-lanes (per q-group):
    // after stage d, lanes whose bit log2(d) of m is set own the upper-half
    // indices. Final: lane m holds the full strip-row sum for idx == m.
#define RS_STAGE(d)                                                     \
    {                                                                   \
        const bool hi = (m & (d)) != 0;                                 \
        _Pragma("unroll")                                               \
        for (int j = 0; j < (d); ++j) {                                 \
            const float va = rs[j], vb = rs[j + (d)];                   \
            const float send = hi ? va : vb;                            \
            const float recv = __shfl_xor(send, (d), 64);               \
            rs[j] = (hi ? vb : va) + recv;                               \
        }                                                               \
    }
    RS_STAGE(8)
    RS_STAGE(4)
    RS_STAGE(2)
    RS_STAGE(1)
#undef RS_STAGE

    // idx == m: it = m>>2, r = m&3; all 64 lanes hit 64 distinct rows.
    // Plain store: (chunk,row) has exactly one writer wave.
    const int row = rowbase + ((m >> 2) << 4) + (q << 2) + (m & 3);
    rowPart[chunk * NB + row] = rs[0];

    // Column combine across the block's 4 waves (strips) -> plain store.
    __syncthreads();
    const int j = threadIdx.x;                 // 0..255
    const float v = (sm[0][j] + sm[1][j]) + (sm[2][j] + sm[3][j]);
    colPart[sgrp * NB + chunk * 256 + j] = v;  // coalesced, unique writer
}

// --------------------------- kernel 3: finish ------------------------------
// 256 blocks x 256 threads: 8 threads per row index i. Thread p of an octet
// sums 4 of the 32 row partials and 4 of the 32 col partials (8 independent
// strided loads, fully latency-overlapped), 3-shuffle octet combine, then
// lane p==0 does the lse/focal math; 64-lane butterfly + block reduce ->
// one scalar atomicAdd per block.
__global__ __launch_bounds__(256)
void finish_kernel(const float* __restrict__ rowPart,
                   const float* __restrict__ colPart,
                   const float* __restrict__ diag,
                   float* __restrict__ out)
{
    const int tg = blockIdx.x * 256 + threadIdx.x;   // 0..65535
    const int i  = tg >> 3;                          // row index 0..8191
    const int p  = threadIdx.x & 7;                  // octet slot

    float rowS = 0.f, colS = 0.f;
    #pragma unroll
    for (int u = 0; u < 4; ++u) {
        rowS += rowPart[(p * 4 + u) * NB + i];
        colS += colPart[(p * 4 + u) * NB + i];
    }
    #pragma unroll
    for (int o = 1; o < 8; o <<= 1) {
        rowS += __shfl_xor(rowS, o, 64);
        colS += __shfl_xor(colS, o, 64);
    }

    float contrib = 0.f;
    if (p == 0) {
        const float d     = diag[i];
        const float lse_r = INV_T + __builtin_amdgcn_logf(rowS) * LN2;
        const float lse_c = INV_T + __builtin_amdgcn_logf(colS) * LN2;
        const float lpr = d - lse_r;
        const float lpc = d - lse_c;
        const float pp  = __builtin_amdgcn_exp2f(lpr * LOG2E);
        const float om  = 1.f - pp;
        contrib = om * om * (-lpr - lpc) * (0.5f / (float)NB);
    }
    // sum the 8 p==0 lanes of the wave (others hold 0)
    #pragma unroll
    for (int o = 8; o < 64; o <<= 1) contrib += __shfl_xor(contrib, o, 64);

    __shared__ float red[4];
    if ((threadIdx.x & 63) == 0) red[threadIdx.x >> 6] = contrib;
    __syncthreads();
    if (threadIdx.x == 0)
        atomicAdd(out, red[0] + red[1] + red[2] + red[3]);
}

// ---------------------------------------------------------------------------
extern "C" void kernel_launch(void* const* d_in, const int* in_sizes, int n_in,
                              void* d_out, int out_size, void* d_ws, size_t ws_size,
                              hipStream_t stream)
{
    const float* img = (const float*)d_in[0];
    const float* txt = (const float*)d_in[1];

    char* ws = (char*)d_ws;
    __hip_bfloat16* imgB = (__hip_bfloat16*)(ws);                        // 1 MB
    __hip_bfloat16* txtB = (__hip_bfloat16*)(ws + (1u << 20));           // 1 MB
    float* diag    = (float*)(ws + (2u << 20));                          // 32 KB
    float* rowPart = (float*)(ws + (2u << 20) + (1u << 15));             // 1 MB
    float* colPart = (float*)(ws + (3u << 20) + (1u << 15));             // 1 MB

    norm_kernel<<<512, 256, 0, stream>>>(img, txt, imgB, txtB, diag, (float*)d_out);
    score_kernel<<<1024, 256, 0, stream>>>(imgB, txtB, rowPart, colPart);
    finish_kernel<<<256, 256, 0, stream>>>(rowPart, colPart, diag, (float*)d_out);
}